// Round 4
// baseline (213.728 us; speedup 1.0000x reference)
//
#include <hip/hip_runtime.h>

#define RAD 6
#define KS 13
#define DIM 192
#define CH 3
#define W4C 48                 // float4 per row
#define PLANE4 (DIM * W4C)     // f4 per (h,w) plane = 9216
#define VOL4 (DIM * PLANE4)    // f4 per channel = 1,769,472
#define VOL (DIM * DIM * DIM)
#define TOTAL (CH * VOL)       // 21,233,664 floats

// Extract 1D gaussian from the 3D kernel: g3[i][j][k] = g1[i]*g1[j]*g1[k], sum(g1)=1,
// so the row-sum over (j,k) recovers g1[i].
__global__ void g1_extract_kernel(const float* __restrict__ w, float* __restrict__ g1) {
    int i = threadIdx.x;
    if (i < KS) {
        float s = 0.f;
        for (int j = 0; j < KS * KS; ++j) s += w[i * KS * KS + j];
        g1[i] = s;
    }
}

// ---------------------------------------------------------------------------
// Kernel 1: fused W-conv + H-conv for one (c, d, h-tile).
// The (h,w) plane at fixed d is CONTIGUOUS in NCDHW, so the LDS slab load is a
// pure sequential copy (fill-kernel-like -> ~6.5 TB/s pattern).
// Tile: h in [h0-6, h0+64+6), full w (48 f4). LDS = 76*48 f4 = 58.4 KB
// -> 2 blocks/CU. Grid: 3c * 192d * 3htiles = 1728 blocks.
// ---------------------------------------------------------------------------
#define HT 64
#define HL (HT + 2 * RAD)      // 76
#define NLD (HL * W4C)         // 3648 f4 in tile

__global__ __launch_bounds__(256) void conv_wh_kernel(const float* __restrict__ in,
                                                      float* __restrict__ out,
                                                      const float* __restrict__ g1) {
    __shared__ float4 tile[NLD];
    const int bid = blockIdx.x;
    const int ht = bid % 3;
    const int d = (bid / 3) % DIM;
    const int c = bid / (3 * DIM);
    const int h0 = ht * HT;
    const int t = threadIdx.x;

    float g[KS];
#pragma unroll
    for (int k = 0; k < KS; ++k) g[k] = g1[k];

    const float4* in4 = (const float4*)in;
    float4* out4 = (float4*)out;
    const size_t plane = (size_t)c * VOL4 + (size_t)d * PLANE4;
    const float4 z4 = make_float4(0.f, 0.f, 0.f, 0.f);

    // ---- load slab: rows h0-6 .. h0+69, full w. Contiguous except h clip. ----
#pragma unroll
    for (int i = 0; i < 15; ++i) {
        int idx = t + i * 256;
        if (idx < NLD) {
            int h = h0 - RAD + idx / W4C;
            tile[idx] = (h >= 0 && h < DIM) ? in4[plane + (size_t)h * W4C + (idx % W4C)] : z4;
        }
    }
    __syncthreads();

    // ---- stage A: W-conv on all 76 rows, results held in registers ----
    float4 va[15];
#pragma unroll
    for (int i = 0; i < 15; ++i) {
        int idx = t + i * 256;
        if (idx < NLD) {
            int row = idx / W4C, w4 = idx % W4C;
            int w0 = w4 * 4;
            float f[20];
#pragma unroll
            for (int b = 0; b < 5; ++b) {
                int j = min(max(w4 + b - 2, 0), W4C - 1);  // clamp; OOB taps zeroed below
                float4 v = tile[row * W4C + j];
                f[4 * b + 0] = v.x; f[4 * b + 1] = v.y;
                f[4 * b + 2] = v.z; f[4 * b + 3] = v.w;
            }
#pragma unroll
            for (int j = 0; j < 20; ++j) {
                int ww = w0 - 8 + j;
                if (ww < 0 || ww >= DIM) f[j] = 0.f;
            }
            float4 o = z4;
#pragma unroll
            for (int k = 0; k < KS; ++k) {
                o.x += g[k] * f[k + 2];
                o.y += g[k] * f[k + 3];
                o.z += g[k] * f[k + 4];
                o.w += g[k] * f[k + 5];
            }
            va[i] = o;
        }
    }
    __syncthreads();  // all stage-A reads done
#pragma unroll
    for (int i = 0; i < 15; ++i) {
        int idx = t + i * 256;
        if (idx < NLD) tile[idx] = va[i];  // write back in place
    }
    __syncthreads();

    // ---- stage B: H-conv via 13-deep LDS sliding window; store to global ----
    // 192 active threads: w4 = t%48, seg = t/48 (4 segs * 16 h outputs).
    if (t < 192) {
        int w4 = t % W4C;
        int seg = t / W4C;
        int hh0 = seg * 16;  // tile-local output row (tile row hh0+j covers h = h0+hh0-6+j)

        // circular window: before step i, buf[(i+j)%13] = tile row hh0+i+j
        float4 buf[KS];
#pragma unroll
        for (int j = 0; j < KS; ++j) buf[j] = tile[(hh0 + j) * W4C + w4];

#pragma unroll
        for (int i = 0; i < 16; ++i) {
            float4 a = z4;
#pragma unroll
            for (int j = 0; j < KS; ++j) {
                const float4 v = buf[(i + j) % KS];
                float gw = g[j];
                a.x += gw * v.x; a.y += gw * v.y; a.z += gw * v.z; a.w += gw * v.w;
            }
            out4[plane + (size_t)(h0 + hh0 + i) * W4C + w4] = a;
            if (i < 15) buf[i % KS] = tile[(hh0 + i + KS) * W4C + w4];  // max row 75 = HL-1
        }
    }
}

// ---------------------------------------------------------------------------
// Kernel 2: D-conv. Full-depth slab in LDS (no halo: whole axis resident).
// Tile: all 192 d * 16 f4 of w at fixed (c,h). LDS = 192*16 f4 = 49.2 KB
// -> 3 blocks/CU. Loads/stores are 256 B contiguous chunks.
// Grid: 3c * 192h * 3wtiles = 1728 blocks.
// ---------------------------------------------------------------------------
#define WT 16

__global__ __launch_bounds__(256) void conv_d_kernel(const float* __restrict__ in,
                                                     float* __restrict__ out,
                                                     const float* __restrict__ g1) {
    __shared__ float4 tile[DIM * WT];
    const int bid = blockIdx.x;
    const int wt = bid % 3;
    const int h = (bid / 3) % DIM;
    const int c = bid / (3 * DIM);
    const int t = threadIdx.x;

    float g[KS];
#pragma unroll
    for (int k = 0; k < KS; ++k) g[k] = g1[k];

    const float4* in4 = (const float4*)in;
    float4* out4 = (float4*)out;
    const size_t base = (size_t)c * VOL4 + (size_t)h * W4C + wt * WT;
    const float4 z4 = make_float4(0.f, 0.f, 0.f, 0.f);

    // ---- load 192 x 16 f4 (12 iters exact; 256 B contiguous per d-row chunk) ----
#pragma unroll
    for (int i = 0; i < 12; ++i) {
        int idx = t + i * 256;
        int dd = idx / WT, w = idx % WT;
        tile[idx] = in4[base + (size_t)dd * PLANE4 + w];
    }
    __syncthreads();

    // ---- conv along d: w = t%16, seg = t/16 (16 segs * 12 d outputs) ----
    int w = t % WT;
    int seg = t / WT;
    int d0 = seg * 12;

    // circular window: before step i, buf[(i+j)%13] = x[d0+i-6+j] (zero OOB)
    float4 buf[KS];
#pragma unroll
    for (int j = 0; j < KS; ++j) {
        int dd = d0 - RAD + j;
        buf[j] = (dd >= 0 && dd < DIM) ? tile[dd * WT + w] : z4;
    }

#pragma unroll
    for (int i = 0; i < 12; ++i) {
        float4 a = z4;
#pragma unroll
        for (int j = 0; j < KS; ++j) {
            const float4 v = buf[(i + j) % KS];
            float gw = g[j];
            a.x += gw * v.x; a.y += gw * v.y; a.z += gw * v.z; a.w += gw * v.w;
        }
        out4[base + (size_t)(d0 + i) * PLANE4 + w] = a;
        if (i < 11) {
            int dl = d0 + i + RAD + 1;
            buf[i % KS] = (dl < DIM) ? tile[dl * WT + w] : z4;
        }
    }
}

// Fallback: direct 2197-tap depthwise conv (only if ws_size is too small).
__global__ void naive_conv3d_kernel(const float* __restrict__ x, const float* __restrict__ w,
                                    float* __restrict__ out, int total) {
    int n = blockIdx.x * blockDim.x + threadIdx.x;
    if (n >= total) return;
    int wp = n % DIM;
    int h = (n / DIM) % DIM;
    int d = (n / (DIM * DIM)) % DIM;
    int c = n / (DIM * DIM * DIM);
    const float* wc = w + c * KS * KS * KS;
    const float* xc = x + (size_t)c * DIM * DIM * DIM;
    float acc = 0.f;
    for (int kd = 0; kd < KS; ++kd) {
        int dd = d + kd - RAD;
        if (dd < 0 || dd >= DIM) continue;
        for (int kh = 0; kh < KS; ++kh) {
            int hh = h + kh - RAD;
            if (hh < 0 || hh >= DIM) continue;
            for (int kw = 0; kw < KS; ++kw) {
                int ww = wp + kw - RAD;
                if (ww < 0 || ww >= DIM) continue;
                acc += wc[(kd * KS + kh) * KS + kw] * xc[((size_t)dd * DIM + hh) * DIM + ww];
            }
        }
    }
    out[n] = acc;
}

extern "C" void kernel_launch(void* const* d_in, const int* in_sizes, int n_in,
                              void* d_out, int out_size, void* d_ws, size_t ws_size,
                              hipStream_t stream) {
    const float* x = (const float*)d_in[0];
    const float* w = (const float*)d_in[1];
    float* out = (float*)d_out;

    const size_t inter_bytes = (size_t)TOTAL * sizeof(float);  // ~85 MB

    if (ws_size >= inter_bytes + 64) {
        float* inter = (float*)d_ws;
        float* g1 = (float*)((char*)d_ws + inter_bytes);

        g1_extract_kernel<<<1, 64, 0, stream>>>(w, g1);

        // Pass 1: fused W+H conv, x -> inter.
        conv_wh_kernel<<<CH * DIM * 3, 256, 0, stream>>>(x, inter, g1);

        // Pass 2: D conv, inter -> out.
        conv_d_kernel<<<CH * DIM * 3, 256, 0, stream>>>(inter, out, g1);
    } else {
        const int threads = 256;
        const int blocks = (TOTAL + threads - 1) / threads;
        naive_conv3d_kernel<<<blocks, threads, 0, stream>>>(x, w, out, TOTAL);
    }
}

// Round 5
// 210.680 us; speedup vs baseline: 1.0145x; 1.0145x over previous
//
#include <hip/hip_runtime.h>

#define RAD 6
#define KS 13
#define DIM 192
#define CH 3
#define W4C 48                 // float4 per row
#define PLANE4 (DIM * W4C)     // f4 per (h,w) plane = 9216
#define VOL4 (DIM * PLANE4)    // f4 per channel
#define VOL (DIM * DIM * DIM)
#define TOTAL (CH * VOL)       // 21,233,664 floats

// Extract 1D gaussian: g3[i][j][k] = g1[i]*g1[j]*g1[k], sum(g1)=1 -> row-sum recovers g1.
__global__ void g1_extract_kernel(const float* __restrict__ w, float* __restrict__ g1) {
    int i = threadIdx.x;
    if (i < KS) {
        float s = 0.f;
        for (int j = 0; j < KS * KS; ++j) s += w[i * KS * KS + j];
        g1[i] = s;
    }
}

// ---------------------------------------------------------------------------
// W-pass: tile = 16 h-rows of one (c,d) plane = 768 f4 = 12 KB LDS.
// Load: 3 unconditional, independent, NON-OVERLAPPING b128 loads per thread
// (pure sequential 12 KB block -> fill-kernel pattern). Each global byte read
// exactly once. Compute reads the 5-f4 window from LDS (overlap is free there).
// 6912 blocks; 12 KB LDS -> 8+ blocks/CU, so load/compute phases overlap.
// ---------------------------------------------------------------------------
__global__ __launch_bounds__(256) void conv_w_lds(const float* __restrict__ in,
                                                  float* __restrict__ out,
                                                  const float* __restrict__ g1) {
    __shared__ float4 tile[768];
    const int bid = blockIdx.x;          // c*DIM*12 + d*12 + rt
    const int rt = bid % 12;
    const int d = (bid / 12) % DIM;
    const int c = bid / (12 * DIM);
    const int t = threadIdx.x;
    const size_t base4 = (size_t)c * VOL4 + (size_t)d * PLANE4 + (size_t)(rt * 16) * W4C;

    const float4* in4 = (const float4*)in;
    float4* out4 = (float4*)out;

    float g[KS];
#pragma unroll
    for (int k = 0; k < KS; ++k) g[k] = g1[k];

#pragma unroll
    for (int i = 0; i < 3; ++i) {
        int idx = t + i * 256;
        tile[idx] = in4[base4 + idx];    // contiguous, exactly-once
    }
    __syncthreads();

#pragma unroll
    for (int i = 0; i < 3; ++i) {
        int idx = t + i * 256;
        int row = idx / W4C, w4 = idx % W4C;
        int w0 = w4 * 4;
        float f[20];
#pragma unroll
        for (int b = 0; b < 5; ++b) {
            int j = min(max(w4 + b - 2, 0), W4C - 1);  // clamp within row; OOB zeroed below
            float4 v = tile[row * W4C + j];
            f[4 * b + 0] = v.x; f[4 * b + 1] = v.y;
            f[4 * b + 2] = v.z; f[4 * b + 3] = v.w;
        }
#pragma unroll
        for (int j = 0; j < 20; ++j) {
            int ww = w0 - 8 + j;
            if (ww < 0 || ww >= DIM) f[j] = 0.f;
        }
        float4 o = make_float4(0.f, 0.f, 0.f, 0.f);
#pragma unroll
        for (int k = 0; k < KS; ++k) {
            o.x += g[k] * f[k + 2];
            o.y += g[k] * f[k + 3];
            o.z += g[k] * f[k + 4];
            o.w += g[k] * f[k + 5];
        }
        out4[base4 + idx] = o;
    }
}

// ---------------------------------------------------------------------------
// Strided-axis pass (H or D): full axis (192) x 16-f4 w-chunk in LDS, padded
// stride 17 to stagger banks (52.2 KB -> 3 blocks/CU). Load: 12 unconditional
// independent non-overlapping b128 loads/thread; wave-load = 4 x 256 B
// segments. Compute: per-thread register sliding window over LDS; zero-pad
// at axis ends (whole axis resident, no halo).
// AXS = axis stride in f4 units (W4C for H-pass, PLANE4 for D-pass).
// ---------------------------------------------------------------------------
#define LPAD 17

template <int AXS>
__global__ __launch_bounds__(256) void conv_axis_lds(const float* __restrict__ in,
                                                     float* __restrict__ out,
                                                     const float* __restrict__ g1) {
    __shared__ float4 tile[DIM * LPAD];
    const int bid = blockIdx.x;          // c*DIM*3 + other*3 + wt
    const int wt = bid % 3;
    const int other = (bid / 3) % DIM;
    const int c = bid / (3 * DIM);
    const int t = threadIdx.x;
    // other coord stride: the non-axis, non-w stride (PLANE4 for H-pass, W4C for D-pass)
    const size_t ostride = (AXS == W4C) ? (size_t)PLANE4 : (size_t)W4C;
    const size_t base4 = (size_t)c * VOL4 + (size_t)other * ostride + (size_t)(wt * 16);

    const float4* in4 = (const float4*)in;
    float4* out4 = (float4*)out;

    float g[KS];
#pragma unroll
    for (int k = 0; k < KS; ++k) g[k] = g1[k];

#pragma unroll
    for (int i = 0; i < 12; ++i) {
        int idx = t + i * 256;
        int p = idx / 16, w = idx % 16;
        tile[p * LPAD + w] = in4[base4 + (size_t)p * AXS + w];  // exactly-once
    }
    __syncthreads();

    const int w = t % 16;
    const int seg = t / 16;              // 16 segs x 12 outputs
    const int p0 = seg * 12;
    const float4 z4 = make_float4(0.f, 0.f, 0.f, 0.f);

    // circular window: before step i, buf[(i+j)%13] = x[p0+i-6+j] (zero OOB)
    float4 buf[KS];
#pragma unroll
    for (int j = 0; j < KS; ++j) {
        int p = p0 - RAD + j;
        buf[j] = (p >= 0 && p < DIM) ? tile[p * LPAD + w] : z4;
    }

#pragma unroll
    for (int i = 0; i < 12; ++i) {
        float4 a = z4;
#pragma unroll
        for (int j = 0; j < KS; ++j) {
            const float4 v = buf[(i + j) % KS];
            float gw = g[j];
            a.x += gw * v.x; a.y += gw * v.y; a.z += gw * v.z; a.w += gw * v.w;
        }
        out4[base4 + (size_t)(p0 + i) * AXS + w] = a;
        if (i < 11) {
            int pl = p0 + i + RAD + 1;
            buf[i % KS] = (pl < DIM) ? tile[pl * LPAD + w] : z4;
        }
    }
}

// Fallback: direct 2197-tap depthwise conv (only if ws_size is too small).
__global__ void naive_conv3d_kernel(const float* __restrict__ x, const float* __restrict__ w,
                                    float* __restrict__ out, int total) {
    int n = blockIdx.x * blockDim.x + threadIdx.x;
    if (n >= total) return;
    int wp = n % DIM;
    int h = (n / DIM) % DIM;
    int d = (n / (DIM * DIM)) % DIM;
    int c = n / (DIM * DIM * DIM);
    const float* wc = w + c * KS * KS * KS;
    const float* xc = x + (size_t)c * DIM * DIM * DIM;
    float acc = 0.f;
    for (int kd = 0; kd < KS; ++kd) {
        int dd = d + kd - RAD;
        if (dd < 0 || dd >= DIM) continue;
        for (int kh = 0; kh < KS; ++kh) {
            int hh = h + kh - RAD;
            if (hh < 0 || hh >= DIM) continue;
            for (int kw = 0; kw < KS; ++kw) {
                int ww = wp + kw - RAD;
                if (ww < 0 || ww >= DIM) continue;
                acc += wc[(kd * KS + kh) * KS + kw] * xc[((size_t)dd * DIM + hh) * DIM + ww];
            }
        }
    }
    out[n] = acc;
}

extern "C" void kernel_launch(void* const* d_in, const int* in_sizes, int n_in,
                              void* d_out, int out_size, void* d_ws, size_t ws_size,
                              hipStream_t stream) {
    const float* x = (const float*)d_in[0];
    const float* w = (const float*)d_in[1];
    float* out = (float*)d_out;

    const size_t inter_bytes = (size_t)TOTAL * sizeof(float);  // ~85 MB

    if (ws_size >= inter_bytes + 64) {
        float* inter = (float*)d_ws;
        float* g1 = (float*)((char*)d_ws + inter_bytes);

        g1_extract_kernel<<<1, 64, 0, stream>>>(w, g1);

        // Pass 1: W axis, x -> out. 6912 blocks, 12 KB LDS tiles.
        conv_w_lds<<<CH * DIM * 12, 256, 0, stream>>>(x, out, g1);

        // Pass 2: H axis (stride W4C, other=d), out -> inter. 1728 blocks.
        conv_axis_lds<W4C><<<CH * DIM * 3, 256, 0, stream>>>(out, inter, g1);

        // Pass 3: D axis (stride PLANE4, other=h), inter -> out. 1728 blocks.
        conv_axis_lds<PLANE4><<<CH * DIM * 3, 256, 0, stream>>>(inter, out, g1);
    } else {
        const int threads = 256;
        const int blocks = (TOTAL + threads - 1) / threads;
        naive_conv3d_kernel<<<blocks, threads, 0, stream>>>(x, w, out, TOTAL);
    }
}

// Round 6
// 191.037 us; speedup vs baseline: 1.1188x; 1.1028x over previous
//
#include <hip/hip_runtime.h>

#define RAD 6
#define KS 13
#define DIM 192
#define CH 3
#define W4C 48                 // float4 per row
#define PLANE4 (DIM * W4C)     // f4 per (h,w) plane = 9216
#define VOL4 (DIM * PLANE4)    // f4 per channel
#define VOL (DIM * DIM * DIM)
#define TOTAL (CH * VOL)       // 21,233,664 floats

// Extract 1D gaussian: g3[i][j][k] = g1[i]*g1[j]*g1[k], sum(g1)=1 -> row-sum recovers g1.
__global__ void g1_extract_kernel(const float* __restrict__ w, float* __restrict__ g1) {
    int i = threadIdx.x;
    if (i < KS) {
        float s = 0.f;
        for (int j = 0; j < KS * KS; ++j) s += w[i * KS * KS + j];
        g1[i] = s;
    }
}

// ---------------------------------------------------------------------------
// Pass 1: fused W-conv + H-conv for one (c, d, h-tile of 32).
// Slab: 48 h-rows (h0-8 .. h0+39) x full w = 2304 f4 = 36.9 KB LDS -> 4 blocks/CU.
// 192 threads: load = 12 exact contiguous b128/thread; stage A = W-conv of the
// same 12 f4 (held in regs across a barrier, written back in place); stage B =
// H-conv, every thread owns one w4 column x 8 output rows via a 13-deep
// register sliding window over LDS. All phases keep all 192 threads busy.
// Grid: 3c * 192d * 6ht = 3456 blocks (13.5/CU).
// ---------------------------------------------------------------------------
#define HT 32
#define HL 48                  // loaded rows (2 rows of slack to make 12*192 exact)
#define NT1 192
#define NLD (HL * W4C)         // 2304 f4

__global__ __launch_bounds__(NT1) void conv_wh2(const float* __restrict__ in,
                                                float* __restrict__ out,
                                                const float* __restrict__ g1) {
    __shared__ float4 tile[NLD];
    const int bid = blockIdx.x;
    const int ht = bid % 6;
    const int d = (bid / 6) % DIM;
    const int c = bid / (6 * DIM);
    const int h0 = ht * HT;
    const int t = threadIdx.x;

    float g[KS];
#pragma unroll
    for (int k = 0; k < KS; ++k) g[k] = g1[k];

    const float4* in4 = (const float4*)in;
    float4* out4 = (float4*)out;
    const size_t plane = (size_t)c * VOL4 + (size_t)d * PLANE4;
    const float4 z4 = make_float4(0.f, 0.f, 0.f, 0.f);

    // ---- load 48 rows (h0-8 .. h0+39), contiguous except h clamp ----
#pragma unroll
    for (int i = 0; i < 12; ++i) {
        int idx = t + i * NT1;
        int row = idx / W4C, w4 = idx % W4C;
        int h = h0 - 8 + row;
        int hc = min(max(h, 0), DIM - 1);             // unconditional load
        float4 v = in4[plane + (size_t)hc * W4C + w4];
        if (h < 0 || h >= DIM) v = z4;                // zero-pad rows
        tile[idx] = v;
    }
    __syncthreads();

    // ---- stage A: W-conv on all 48 rows; results in regs across the barrier ----
    float4 va[12];
#pragma unroll
    for (int i = 0; i < 12; ++i) {
        int idx = t + i * NT1;
        int row = idx / W4C, w4 = idx % W4C;
        int w0 = w4 * 4;
        float f[20];
#pragma unroll
        for (int b = 0; b < 5; ++b) {
            int j = min(max(w4 + b - 2, 0), W4C - 1);  // clamp; OOB taps zeroed below
            float4 v = tile[row * W4C + j];
            f[4 * b + 0] = v.x; f[4 * b + 1] = v.y;
            f[4 * b + 2] = v.z; f[4 * b + 3] = v.w;
        }
#pragma unroll
        for (int j = 0; j < 20; ++j) {
            int ww = w0 - 8 + j;
            if (ww < 0 || ww >= DIM) f[j] = 0.f;
        }
        float4 o = z4;
#pragma unroll
        for (int k = 0; k < KS; ++k) {
            o.x += g[k] * f[k + 2];
            o.y += g[k] * f[k + 3];
            o.z += g[k] * f[k + 4];
            o.w += g[k] * f[k + 5];
        }
        va[i] = o;
    }
    __syncthreads();
#pragma unroll
    for (int i = 0; i < 12; ++i) tile[t + i * NT1] = va[i];
    __syncthreads();

    // ---- stage B: H-conv. thread = (w4, rg); 4 rgs x 8 rows = 32 output rows ----
    const int w4 = t % W4C;
    const int rg = t / W4C;
    const int i0 = rg * 8;
    // output row i (tile h = h0+i) needs tile rows i+2 .. i+14 (tile row r = h0-8+r).
    float4 buf[KS];
#pragma unroll
    for (int j = 0; j < KS; ++j) buf[j] = tile[(i0 + 2 + j) * W4C + w4];

#pragma unroll
    for (int ii = 0; ii < 8; ++ii) {
        float4 a = z4;
#pragma unroll
        for (int j = 0; j < KS; ++j) {
            const float4 v = buf[(ii + j) % KS];
            float gw = g[j];
            a.x += gw * v.x; a.y += gw * v.y; a.z += gw * v.z; a.w += gw * v.w;
        }
        out4[plane + (size_t)(h0 + i0 + ii) * W4C + w4] = a;
        if (ii < 7) buf[ii % KS] = tile[(i0 + ii + 15) * W4C + w4];  // max row 45 < 48
    }
}

// ---------------------------------------------------------------------------
// Pass 2: D-conv. Full-depth slab, w-chunk of 8 f4 at fixed (c,h).
// LDS = 192*8 f4 = 24.6 KB -> 6 blocks/CU. 256 threads: load = 6 exact
// independent b128/thread (8 x 128 B chunks per wave at plane stride);
// compute: 32 segs x 6 outputs via register sliding window (full axis
// resident, zero-pad at ends). Grid: 3c * 192h * 6wt = 3456 blocks.
// ---------------------------------------------------------------------------
__global__ __launch_bounds__(256) void conv_d8(const float* __restrict__ in,
                                               float* __restrict__ out,
                                               const float* __restrict__ g1) {
    __shared__ float4 tile[DIM * 8];
    const int bid = blockIdx.x;
    const int wt = bid % 6;
    const int h = (bid / 6) % DIM;
    const int c = bid / (6 * DIM);
    const int t = threadIdx.x;

    float g[KS];
#pragma unroll
    for (int k = 0; k < KS; ++k) g[k] = g1[k];

    const float4* in4 = (const float4*)in;
    float4* out4 = (float4*)out;
    const size_t base4 = (size_t)c * VOL4 + (size_t)h * W4C + wt * 8;
    const float4 z4 = make_float4(0.f, 0.f, 0.f, 0.f);

#pragma unroll
    for (int i = 0; i < 6; ++i) {
        int idx = t + i * 256;
        int dd = idx / 8, w = idx % 8;
        tile[idx] = in4[base4 + (size_t)dd * PLANE4 + w];   // exactly-once
    }
    __syncthreads();

    const int w = t % 8;
    const int seg = t / 8;       // 32 segs x 6 outputs
    const int d0 = seg * 6;

    float4 buf[KS];
#pragma unroll
    for (int j = 0; j < KS; ++j) {
        int p = d0 - RAD + j;
        buf[j] = (p >= 0 && p < DIM) ? tile[p * 8 + w] : z4;
    }

#pragma unroll
    for (int i = 0; i < 6; ++i) {
        float4 a = z4;
#pragma unroll
        for (int j = 0; j < KS; ++j) {
            const float4 v = buf[(i + j) % KS];
            float gw = g[j];
            a.x += gw * v.x; a.y += gw * v.y; a.z += gw * v.z; a.w += gw * v.w;
        }
        out4[base4 + (size_t)(d0 + i) * PLANE4 + w] = a;
        if (i < 5) {
            int p = d0 + i + RAD + 1;
            buf[i % KS] = (p < DIM) ? tile[p * 8 + w] : z4;
        }
    }
}

// Fallback: direct 2197-tap depthwise conv (only if ws_size is too small).
__global__ void naive_conv3d_kernel(const float* __restrict__ x, const float* __restrict__ w,
                                    float* __restrict__ out, int total) {
    int n = blockIdx.x * blockDim.x + threadIdx.x;
    if (n >= total) return;
    int wp = n % DIM;
    int h = (n / DIM) % DIM;
    int d = (n / (DIM * DIM)) % DIM;
    int c = n / (DIM * DIM * DIM);
    const float* wc = w + c * KS * KS * KS;
    const float* xc = x + (size_t)c * DIM * DIM * DIM;
    float acc = 0.f;
    for (int kd = 0; kd < KS; ++kd) {
        int dd = d + kd - RAD;
        if (dd < 0 || dd >= DIM) continue;
        for (int kh = 0; kh < KS; ++kh) {
            int hh = h + kh - RAD;
            if (hh < 0 || hh >= DIM) continue;
            for (int kw = 0; kw < KS; ++kw) {
                int ww = wp + kw - RAD;
                if (ww < 0 || ww >= DIM) continue;
                acc += wc[(kd * KS + kh) * KS + kw] * xc[((size_t)dd * DIM + hh) * DIM + ww];
            }
        }
    }
    out[n] = acc;
}

extern "C" void kernel_launch(void* const* d_in, const int* in_sizes, int n_in,
                              void* d_out, int out_size, void* d_ws, size_t ws_size,
                              hipStream_t stream) {
    const float* x = (const float*)d_in[0];
    const float* w = (const float*)d_in[1];
    float* out = (float*)d_out;

    const size_t inter_bytes = (size_t)TOTAL * sizeof(float);  // ~85 MB

    if (ws_size >= inter_bytes + 64) {
        float* inter = (float*)d_ws;
        float* g1 = (float*)((char*)d_ws + inter_bytes);

        g1_extract_kernel<<<1, 64, 0, stream>>>(w, g1);

        // Pass 1: fused W+H conv, x -> inter. 3456 blocks, 36.9 KB LDS.
        conv_wh2<<<CH * DIM * 6, NT1, 0, stream>>>(x, inter, g1);

        // Pass 2: D conv, inter -> out. 3456 blocks, 24.6 KB LDS.
        conv_d8<<<CH * DIM * 6, 256, 0, stream>>>(inter, out, g1);
    } else {
        const int threads = 256;
        const int blocks = (TOTAL + threads - 1) / threads;
        naive_conv3d_kernel<<<blocks, threads, 0, stream>>>(x, w, out, TOTAL);
    }
}